// Round 1
// baseline (342.758 us; speedup 1.0000x reference)
//
#include <hip/hip_runtime.h>
#include <math.h>

#define UNITS 100000
#define BATCH 512
#define DIM 512
#define BN 64
#define NBLK ((UNITS + BN - 1) / BN)   /* 1563 */
#define SCALE 64.0f
#define COS_M2 0.87758256189037271612f  /* cos(0.5) */
#define SIN_M2 0.47942553860420300027f  /* sin(0.5) */

typedef _Float16 half8 __attribute__((ext_vector_type(8)));
typedef float floatx4 __attribute__((ext_vector_type(4)));

// ---------------- Kernel 1: row-normalize inputs -> fp16 A [512][512] ----------------
__global__ void norm_emb_k(const float* __restrict__ inp, _Float16* __restrict__ A) {
    const int row = blockIdx.x;
    const int lane = threadIdx.x;             // 64 threads = 1 wave
    const float* rp = inp + row * DIM + lane * 8;
    float v[8];
#pragma unroll
    for (int j = 0; j < 8; ++j) v[j] = rp[j];
    float ss = 0.f;
#pragma unroll
    for (int j = 0; j < 8; ++j) ss += v[j] * v[j];
#pragma unroll
    for (int off = 32; off > 0; off >>= 1) ss += __shfl_xor(ss, off);
    const float inv = 1.0f / sqrtf(ss);
    half8 h;
#pragma unroll
    for (int j = 0; j < 8; ++j) h[j] = (_Float16)(v[j] * inv);
    *(half8*)(A + row * DIM + lane * 8) = h;
}

// ---------------- Kernel 2: fused GEMM + col-norm + margin + exp + row partial sums ----
// Block: 512 threads (8 waves). Block computes all 512 rows x BN=64 cols.
// Wave w owns rows [w*64, w*64+64): 4(M) x 4(N) fragments of 16x16, K-step 32.
__global__ __launch_bounds__(512) void gemm_exp_k(
    const float* __restrict__ w, const _Float16* __restrict__ A,
    const int* __restrict__ label, float* __restrict__ out,
    float* __restrict__ partials) {
    // Bt[buf][kgrp][col][8]: k-major fp16 tile of w^T for MFMA B fragments
    __shared__ _Float16 Bt[2][4][BN][8];
    __shared__ float scratch[32][BN];
    __shared__ float cninv_s[BN];

    const int t = threadIdx.x;
    const int blk = blockIdx.x;
    const int c0 = blk * BN;
    const int kk = t >> 4;             // 0..31 : k row within K-step
    const int c4 = (t & 15) * 4;       // 0..60 : 4 cols per thread
    const bool sv = (c0 + c4) < UNITS; // tail block guard (32-col tail, float4-aligned)

    const int wid = t >> 6;
    const int lane = t & 63;
    const int colg = lane & 15;
    const int rowg = lane >> 4;
    const int rowbase = wid * 64;

    float sq[4] = {0.f, 0.f, 0.f, 0.f};

    floatx4 acc[4][4];
#pragma unroll
    for (int mf = 0; mf < 4; ++mf)
#pragma unroll
        for (int nf = 0; nf < 4; ++nf) acc[mf][nf] = (floatx4){0.f, 0.f, 0.f, 0.f};

    // ---- staging helpers ----
    auto load_step = [&](int ks) -> float4 {
        if (sv) return *(const float4*)(w + (ks * 32 + kk) * UNITS + c0 + c4);
        return make_float4(0.f, 0.f, 0.f, 0.f);
    };
    auto write_step = [&](int buf, const float4& u) {
        sq[0] += u.x * u.x; sq[1] += u.y * u.y; sq[2] += u.z * u.z; sq[3] += u.w * u.w;
        _Float16* p = &Bt[buf][kk >> 3][c4][kk & 7];
        p[0]  = (_Float16)u.x;
        p[8]  = (_Float16)u.y;
        p[16] = (_Float16)u.z;
        p[24] = (_Float16)u.w;
    };

    // prologue
    float4 cur = load_step(0);
    write_step(0, cur);
    __syncthreads();

    const _Float16* Abase = A + (rowbase + colg) * DIM + rowg * 8;

    for (int ks = 0; ks < 16; ++ks) {
        float4 nxt;
        if (ks < 15) nxt = load_step(ks + 1);   // issue next-tile loads early (hide HBM)
        const int buf = ks & 1;
        half8 a[4], b[4];
#pragma unroll
        for (int mf = 0; mf < 4; ++mf)
            a[mf] = *(const half8*)(Abase + mf * 16 * DIM + ks * 32);   // L2-resident A
#pragma unroll
        for (int nf = 0; nf < 4; ++nf)
            b[nf] = *(const half8*)(&Bt[buf][rowg][nf * 16 + colg][0]);
#pragma unroll
        for (int mf = 0; mf < 4; ++mf)
#pragma unroll
            for (int nf = 0; nf < 4; ++nf)
                acc[mf][nf] = __builtin_amdgcn_mfma_f32_16x16x32_f16(a[mf], b[nf], acc[mf][nf], 0, 0, 0);
        if (ks < 15) {
            __syncthreads();
            write_step(buf ^ 1, nxt);
            __syncthreads();
        }
    }
    __syncthreads();

    // ---- column norms (from f32 staged values, matches reference wn = w/||w||) ----
#pragma unroll
    for (int j = 0; j < 4; ++j) scratch[kk][c4 + j] = sq[j];
    __syncthreads();
    if (t < BN) {
        float s = 0.f;
#pragma unroll
        for (int k2 = 0; k2 < 32; ++k2) s += scratch[k2][t];
        cninv_s[t] = 1.0f / sqrtf(s);
    }
    __syncthreads();

    // ---- epilogue: normalize, margin at label col, exp, store, row partial sums ----
    float rs[4][4];
#pragma unroll
    for (int mf = 0; mf < 4; ++mf)
#pragma unroll
        for (int r = 0; r < 4; ++r) rs[mf][r] = 0.f;

#pragma unroll
    for (int mf = 0; mf < 4; ++mf) {
        const int Rb = rowbase + mf * 16 + rowg * 4;
        int labs[4];
#pragma unroll
        for (int r = 0; r < 4; ++r) labs[r] = label[Rb + r];
#pragma unroll
        for (int nf = 0; nf < 4; ++nf) {
            const int C = c0 + nf * 16 + colg;
            const bool cv = C < UNITS;
            const float cni = cninv_s[nf * 16 + colg];
#pragma unroll
            for (int r = 0; r < 4; ++r) {
                float cs = acc[mf][nf][r] * cni;   // cos(theta), emb & w both unit
                float lg;
                if (C == labs[r]) {
                    cs = fminf(1.f, fmaxf(-1.f, cs));
                    // cos(t + 0.5) = cos t * cos .5 - sin t * sin .5, sin t = sqrt(1-cos^2)
                    lg = SCALE * (cs * COS_M2 - sqrtf(fmaxf(0.f, 1.f - cs * cs)) * SIN_M2);
                } else {
                    lg = SCALE * cs;
                }
                float e = cv ? expf(lg) : 0.f;     // max logit 64 -> exp(64)=6e27, no overflow
                if (cv) out[(Rb + r) * UNITS + C] = e;
                rs[mf][r] += e;
            }
        }
    }
    // reduce across the 16-lane column group (deterministic, no atomics)
#pragma unroll
    for (int mf = 0; mf < 4; ++mf)
#pragma unroll
        for (int r = 0; r < 4; ++r) {
            float s = rs[mf][r];
            s += __shfl_xor(s, 1);
            s += __shfl_xor(s, 2);
            s += __shfl_xor(s, 4);
            s += __shfl_xor(s, 8);
            rs[mf][r] = s;
        }
    if (colg == 0) {
#pragma unroll
        for (int mf = 0; mf < 4; ++mf)
#pragma unroll
            for (int r = 0; r < 4; ++r)
                partials[(rowbase + mf * 16 + rowg * 4 + r) * NBLK + blk] = rs[mf][r];
    }
}

// ---------------- Kernel 3: row sums -> 1/sum ----------------
__global__ void rowsum_k(const float* __restrict__ partials, float* __restrict__ inv) {
    const int row = blockIdx.x;
    const int lane = threadIdx.x;   // 64
    float s = 0.f;
    for (int b = lane; b < NBLK; b += 64) s += partials[row * NBLK + b];
#pragma unroll
    for (int off = 32; off > 0; off >>= 1) s += __shfl_xor(s, off);
    if (lane == 0) inv[row] = 1.0f / s;
}

// ---------------- Kernel 4: scale by 1/rowsum ----------------
__global__ void scale_k(float* __restrict__ out, const float* __restrict__ inv) {
    const int total4 = BATCH * (UNITS / 4);   // 12.8M float4
    int i = blockIdx.x * blockDim.x + threadIdx.x;
    const int stride = gridDim.x * blockDim.x;
    for (; i < total4; i += stride) {
        float4 v = ((const float4*)out)[i];
        const float s = inv[i / (UNITS / 4)];
        v.x *= s; v.y *= s; v.z *= s; v.w *= s;
        ((float4*)out)[i] = v;
    }
}

extern "C" void kernel_launch(void* const* d_in, const int* in_sizes, int n_in,
                              void* d_out, int out_size, void* d_ws, size_t ws_size,
                              hipStream_t stream) {
    const float* inp   = (const float*)d_in[0];
    const int*   label = (const int*)d_in[1];
    const float* w     = (const float*)d_in[2];
    float* out = (float*)d_out;

    char* ws = (char*)d_ws;
    _Float16* A     = (_Float16*)ws;                                   // 512 KB
    float* partials = (float*)(ws + (size_t)BATCH * DIM * 2);          // 512*1563*4 = 3.2 MB
    float* inv      = (float*)(ws + (size_t)BATCH * DIM * 2 + (size_t)BATCH * NBLK * 4);

    norm_emb_k<<<BATCH, 64, 0, stream>>>(inp, A);
    gemm_exp_k<<<NBLK, 512, 0, stream>>>(w, A, label, out, partials);
    rowsum_k<<<BATCH, 64, 0, stream>>>(partials, inv);
    scale_k<<<2048, 256, 0, stream>>>(out, inv);
}

// Round 2
// 233.611 us; speedup vs baseline: 1.4672x; 1.4672x over previous
//
#include <hip/hip_runtime.h>
#include <math.h>

#define UNITS 100000
#define BATCH 512
#define DIM 512
#define BN 64
#define NBLK ((UNITS + BN - 1) / BN)   /* 1563 */
#define SCALE 64.0f
#define COS_M2 0.87758256189037271612f  /* cos(0.5) */
#define SIN_M2 0.47942553860420300027f  /* sin(0.5) */
#define LOG2E  1.44269504088896340736f

typedef _Float16 half8 __attribute__((ext_vector_type(8)));
typedef float floatx4 __attribute__((ext_vector_type(4)));

// ---------------- Kernel 1: row-normalize inputs -> fragment-ordered fp16 A2 ----------
// A2[rt][ks][slot][8]: slot = (row&15) + 16*q holds A[rt*16+(row&15)][ks*32+q*8 .. +8]
// so a GEMM wave's A-frag load is 64 lanes x 16B contiguous (1KB).
__global__ void norm_emb_k(const float* __restrict__ inp, _Float16* __restrict__ A2) {
    const int row = blockIdx.x;
    const int lane = threadIdx.x;             // 64 threads = 1 wave
    const float* rp = inp + row * DIM + lane * 8;
    float v[8];
#pragma unroll
    for (int j = 0; j < 8; ++j) v[j] = rp[j];
    float ss = 0.f;
#pragma unroll
    for (int j = 0; j < 8; ++j) ss += v[j] * v[j];
#pragma unroll
    for (int off = 32; off > 0; off >>= 1) ss += __shfl_xor(ss, off);
    const float inv = 1.0f / sqrtf(ss);
    half8 h;
#pragma unroll
    for (int j = 0; j < 8; ++j) h[j] = (_Float16)(v[j] * inv);
    // thread's 8 halfs are k = lane*8..+7 -> ks = lane>>2, q = lane&3
    const int idx = ((((row >> 4) * 16 + (lane >> 2)) * 64) + (row & 15) + 16 * (lane & 3)) * 8;
    *(half8*)(A2 + idx) = h;
}

// ---------------- Kernel 2: fused GEMM + col-norm + margin + shifted-exp + partials ----
// Block: 512 threads (8 waves), tile = all 512 rows x BN=64 cols, full K staged once.
template<bool HALF>
__global__ __launch_bounds__(512, 4) void gemm_exp_k(
    const float* __restrict__ w, const _Float16* __restrict__ A2,
    const int* __restrict__ label,
    float* __restrict__ outf, _Float16* __restrict__ outh,
    float* __restrict__ psum, float* __restrict__ pmax) {
    __shared__ _Float16 Bt[64][64][8];   // [kgrp][col][k&7], 64KB
    __shared__ float scratch[32][68];    // padded, 8.7KB
    __shared__ float cninv_s[64];

    const int t = threadIdx.x;
    const int blk = blockIdx.x;
    const int c0 = blk * BN;
    const int kk = t >> 4;               // 0..31
    const int ci = t & 15;               // col base; thread covers cols ci+16j

    bool valid[4];
#pragma unroll
    for (int j = 0; j < 4; ++j) valid[j] = (c0 + ci + 16 * j) < UNITS;

    // ---- staging: full 512-k x 64-col tile -> fp16 LDS, strided cols (bank-clean) ----
    float sq[4] = {0.f, 0.f, 0.f, 0.f};
    float va[4][4], vb[4][4];

    auto issue = [&](int g, float (*dst)[4]) {
#pragma unroll
        for (int c = 0; c < 4; ++c) {
            const float* p = w + (size_t)((g * 4 + c) * 32 + kk) * UNITS + c0 + ci;
#pragma unroll
            for (int j = 0; j < 4; ++j) dst[c][j] = valid[j] ? p[16 * j] : 0.f;
        }
    };
    auto consume = [&](int g, float (*src)[4]) {
#pragma unroll
        for (int c = 0; c < 4; ++c) {
            const int k = (g * 4 + c) * 32 + kk;
#pragma unroll
            for (int j = 0; j < 4; ++j) {
                const float x = src[c][j];
                sq[j] += x * x;
                Bt[k >> 3][ci + 16 * j][k & 7] = (_Float16)x;
            }
        }
    };
    issue(0, va);
    issue(1, vb);
    consume(0, va);
    issue(2, va);
    consume(1, vb);
    issue(3, vb);
    consume(2, va);
    consume(3, vb);

#pragma unroll
    for (int j = 0; j < 4; ++j) scratch[kk][ci + 16 * j] = sq[j];
    __syncthreads();
    if (t < 64) {
        float s = 0.f;
#pragma unroll
        for (int k2 = 0; k2 < 32; ++k2) s += scratch[k2][t];
        cninv_s[t] = 1.0f / sqrtf(s);
    }
    __syncthreads();

    // ---- barrier-free MFMA loop ----
    const int wid = t >> 6;
    const int lane = t & 63;
    const int colg = lane & 15;
    const int rowg = lane >> 4;
    const int rowbase = wid * 64;

    floatx4 acc[4][4];
#pragma unroll
    for (int mf = 0; mf < 4; ++mf)
#pragma unroll
        for (int nf = 0; nf < 4; ++nf) acc[mf][nf] = (floatx4){0.f, 0.f, 0.f, 0.f};

#pragma unroll 2
    for (int ks = 0; ks < 16; ++ks) {
        half8 b[4];
#pragma unroll
        for (int nf = 0; nf < 4; ++nf)
            b[nf] = *(const half8*)(&Bt[ks * 4 + rowg][nf * 16 + colg][0]);
#pragma unroll
        for (int mf = 0; mf < 4; ++mf) {
            const half8 a = *(const half8*)(A2 + ((((wid * 4 + mf) * 16) + ks) * 64 + lane) * 8);
#pragma unroll
            for (int nf = 0; nf < 4; ++nf)
                acc[mf][nf] = __builtin_amdgcn_mfma_f32_16x16x32_f16(a, b[nf], acc[mf][nf], 0, 0, 0);
        }
    }

    // ---- epilogue: normalize, margin, per-(row,tile) max-shifted exp, partial sums ----
    float inv_cn[4];
#pragma unroll
    for (int nf = 0; nf < 4; ++nf) inv_cn[nf] = cninv_s[nf * 16 + colg];

#pragma unroll
    for (int mf = 0; mf < 4; ++mf) {
#pragma unroll
        for (int r = 0; r < 4; ++r) {
            const int R = rowbase + mf * 16 + rowg * 4 + r;
            const int labv = label[R];
            float lg[4];
            float mx = -1e30f;
#pragma unroll
            for (int nf = 0; nf < 4; ++nf) {
                const int C = c0 + nf * 16 + colg;
                float cs = acc[mf][nf][r] * inv_cn[nf];
                float x;
                if (C == labv) {
                    cs = fminf(1.f, fmaxf(-1.f, cs));
                    x = SCALE * (cs * COS_M2 - sqrtf(fmaxf(0.f, 1.f - cs * cs)) * SIN_M2);
                } else {
                    x = SCALE * cs;
                }
                if (C >= UNITS) x = -1e30f;
                lg[nf] = x;
                mx = fmaxf(mx, x);
            }
            mx = fmaxf(mx, __shfl_xor(mx, 1));
            mx = fmaxf(mx, __shfl_xor(mx, 2));
            mx = fmaxf(mx, __shfl_xor(mx, 4));
            mx = fmaxf(mx, __shfl_xor(mx, 8));
            float s = 0.f;
#pragma unroll
            for (int nf = 0; nf < 4; ++nf) {
                const int C = c0 + nf * 16 + colg;
                const float e = exp2f((lg[nf] - mx) * LOG2E);
                s += (C < UNITS) ? e : 0.f;
                if (C < UNITS) {
                    if (HALF) outh[(size_t)R * UNITS + C] = (_Float16)e;
                    else      outf[(size_t)R * UNITS + C] = e;
                }
            }
            s += __shfl_xor(s, 1);
            s += __shfl_xor(s, 2);
            s += __shfl_xor(s, 4);
            s += __shfl_xor(s, 8);
            if (colg == 0) {
                psum[R * NBLK + blk] = s;
                pmax[R * NBLK + blk] = mx;
            }
        }
    }
}

// ---------------- Kernel 3: per-row global max + sum -> per-(row,tile) factor ----------
__global__ void rowfac_k(const float* __restrict__ psum, const float* __restrict__ pmax,
                         float* __restrict__ fac) {
    const int row = blockIdx.x;
    const int lane = threadIdx.x;   // 64
    float mx = -1e30f;
    for (int b = lane; b < NBLK; b += 64) mx = fmaxf(mx, pmax[row * NBLK + b]);
#pragma unroll
    for (int off = 32; off > 0; off >>= 1) mx = fmaxf(mx, __shfl_xor(mx, off));
    float s = 0.f;
    for (int b = lane; b < NBLK; b += 64)
        s += psum[row * NBLK + b] * exp2f((pmax[row * NBLK + b] - mx) * LOG2E);
#pragma unroll
    for (int off = 32; off > 0; off >>= 1) s += __shfl_xor(s, off);
    const float invS = 1.0f / s;
    for (int b = lane; b < NBLK; b += 64)
        fac[row * NBLK + b] = exp2f((pmax[row * NBLK + b] - mx) * LOG2E) * invS;
}

// ---------------- Kernel 4: scale ----------------
__global__ void scale_half_k(const _Float16* __restrict__ v, const float* __restrict__ fac,
                             float* __restrict__ out) {
    const int row = blockIdx.y;
    const int c = (blockIdx.x * 256 + threadIdx.x) * 8;
    if (c >= UNITS) return;
    const float f = fac[row * NBLK + (c >> 6)];
    const half8 h = *(const half8*)(v + (size_t)row * UNITS + c);
    float4 o1, o2;
    o1.x = (float)h[0] * f; o1.y = (float)h[1] * f; o1.z = (float)h[2] * f; o1.w = (float)h[3] * f;
    o2.x = (float)h[4] * f; o2.y = (float)h[5] * f; o2.z = (float)h[6] * f; o2.w = (float)h[7] * f;
    float* op = out + (size_t)row * UNITS + c;
    *(float4*)op = o1;
    *(float4*)(op + 4) = o2;
}

__global__ void scale_f32_k(float* __restrict__ out, const float* __restrict__ fac) {
    const int row = blockIdx.y;
    const int c = (blockIdx.x * 256 + threadIdx.x) * 8;
    if (c >= UNITS) return;
    const float f = fac[row * NBLK + (c >> 6)];
    float* op = out + (size_t)row * UNITS + c;
    float4 o1 = *(float4*)op;
    float4 o2 = *(float4*)(op + 4);
    o1.x *= f; o1.y *= f; o1.z *= f; o1.w *= f;
    o2.x *= f; o2.y *= f; o2.z *= f; o2.w *= f;
    *(float4*)op = o1;
    *(float4*)(op + 4) = o2;
}

extern "C" void kernel_launch(void* const* d_in, const int* in_sizes, int n_in,
                              void* d_out, int out_size, void* d_ws, size_t ws_size,
                              hipStream_t stream) {
    const float* inp   = (const float*)d_in[0];
    const int*   label = (const int*)d_in[1];
    const float* w     = (const float*)d_in[2];
    float* out = (float*)d_out;

    char* ws = (char*)d_ws;
    _Float16* A2   = (_Float16*)ws;                                  // 512 KB
    float* psum    = (float*)(ws + (1 << 20));                       // 3.2 MB
    float* pmax    = (float*)(ws + (1 << 20) + 4 * BATCH * NBLK);    // 3.2 MB
    float* fac     = (float*)(ws + (1 << 20) + 8 * BATCH * NBLK);    // 3.2 MB
    _Float16* vh   = (_Float16*)(ws + (16 << 20));                   // 102.4 MB
    const size_t need = (size_t)(16 << 20) + (size_t)BATCH * UNITS * 2;
    const bool half_path = ws_size >= need;

    norm_emb_k<<<BATCH, 64, 0, stream>>>(inp, A2);
    if (half_path)
        gemm_exp_k<true><<<NBLK, 512, 0, stream>>>(w, A2, label, out, vh, psum, pmax);
    else
        gemm_exp_k<false><<<NBLK, 512, 0, stream>>>(w, A2, label, out, vh, psum, pmax);
    rowfac_k<<<BATCH, 64, 0, stream>>>(psum, pmax, fac);
    dim3 sg((UNITS + 2047) / 2048, BATCH);
    if (half_path)
        scale_half_k<<<sg, 256, 0, stream>>>(vh, fac, out);
    else
        scale_f32_k<<<sg, 256, 0, stream>>>(out, fac);
}